// Round 5
// baseline (180.591 us; speedup 1.0000x reference)
//
#include <hip/hip_runtime.h>
#include <math.h>

// B=65536 rows, N=1024 cols, fp32.
//   t_b = argmax_c target[b,c]  (first-max tie-break)
//   out = mean_b(-log(y[b,t_b]+1e-8)) + sum_{b,c} w[popc(t_b^c)]*y[b,c]/(B*N),  w[p]=(p==0)?0:6^p
// R4 evidence: still latency-bound (hbm 21%, VALU 13%). Demand BW 5.3 TB/s vs 6.7 ceiling.
// Fix: 4-row phase-split — y-loads issued BEFORE the cross-lane chains (latency hides
// under chains), 4 interleaved shuffle chains amortize DS latency.

#define B_ROWS 65536
#define N_COLS 1024
#define WAVES_PER_BLOCK 4
#define ROWS_BLOCKS 2048
#define ROWS_THREADS (WAVES_PER_BLOCK * 64)
#define NWAVES (ROWS_BLOCKS * WAVES_PER_BLOCK)  // 8192 waves; 8 rows/wave = 2 iters x 4 rows

__device__ __forceinline__ float pick16(const float4* yr, int t) {
    // select element for column t from this lane's 4 float4s (runtime k,e -> cndmask chain)
    const int k = t >> 8;  // which float4 (cols 256 apart per k)
    const int e = t & 3;
    float4 s = (k & 2) ? ((k & 1) ? yr[3] : yr[2]) : ((k & 1) ? yr[1] : yr[0]);
    return (e & 2) ? ((e & 1) ? s.w : s.z) : ((e & 1) ? s.y : s.x);
}

__global__ __launch_bounds__(ROWS_THREADS)
void ce_rows_kernel(const float* __restrict__ y_true,
                    const float* __restrict__ target,
                    float* __restrict__ partials) {
    __shared__ float w_lds[16];
    __shared__ float wave_part[WAVES_PER_BLOCK];

    const int tid = threadIdx.x;
    if (tid < 16) {
        float w = 1.0f;
        for (int p = 0; p < tid; ++p) w *= 6.0f;   // exact: 6^10 < 2^26
        w_lds[tid] = (tid == 0) ? 0.0f : w;
    }
    __syncthreads();

    const int lane  = tid & 63;
    const int wid   = tid >> 6;
    const int gwave = blockIdx.x * WAVES_PER_BLOCK + wid;

    float acc_pt = 0.0f;   // lane-private weighted-sum partial (unscaled)
    float acc_lg = 0.0f;   // lane-private sum of log(y[t]+1e-8), owner lanes only

    #pragma unroll 1
    for (int it = 0; it < 2; ++it) {
        const int base = gwave + it * 4 * NWAVES;

        // ---- phase 1: load 4 target rows (all 16 float4 loads independent) ----
        float4 t4[4][4];
        #pragma unroll
        for (int r = 0; r < 4; ++r) {
            const float4* tp = (const float4*)(target + (size_t)(base + r * NWAVES) * N_COLS);
            #pragma unroll
            for (int k = 0; k < 4; ++k) t4[r][k] = tp[lane + 64 * k];
        }

        // ---- phase 2: local argmax per row (frees t4 regs); strict > = first-index ----
        float bv[4]; int bi[4];
        #pragma unroll
        for (int r = 0; r < 4; ++r) {
            bv[r] = -1.0f; bi[r] = 0;
            #pragma unroll
            for (int k = 0; k < 4; ++k) {
                const int c0 = 4 * (lane + 64 * k);
                const float4 v = t4[r][k];
                if (v.x > bv[r]) { bv[r] = v.x; bi[r] = c0;     }
                if (v.y > bv[r]) { bv[r] = v.y; bi[r] = c0 + 1; }
                if (v.z > bv[r]) { bv[r] = v.z; bi[r] = c0 + 2; }
                if (v.w > bv[r]) { bv[r] = v.w; bi[r] = c0 + 3; }
            }
        }

        // ---- phase 3: issue all 4 y rows' loads (latency hides under the chains) ----
        float4 y4[4][4];
        #pragma unroll
        for (int r = 0; r < 4; ++r) {
            const float4* yp = (const float4*)(y_true + (size_t)(base + r * NWAVES) * N_COLS);
            #pragma unroll
            for (int k = 0; k < 4; ++k) y4[r][k] = yp[lane + 64 * k];
        }

        // ---- phase 4: cross-lane argmax, 4 independent chains interleaved ----
        #pragma unroll
        for (int m = 32; m >= 1; m >>= 1) {
            #pragma unroll
            for (int r = 0; r < 4; ++r) {
                const float ov = __shfl_xor(bv[r], m, 64);
                const int   oi = __shfl_xor(bi[r], m, 64);
                if (ov > bv[r] || (ov == bv[r] && oi < bi[r])) { bv[r] = ov; bi[r] = oi; }
            }
        }

        // ---- phase 5: weighted sum (lane-private, no reduction) + owner-lane CE ----
        #pragma unroll
        for (int r = 0; r < 4; ++r) {
            const int t = bi[r];   // wave-uniform
            #pragma unroll
            for (int k = 0; k < 4; ++k) {
                const int x = t ^ (4 * (lane + 64 * k));   // popc keys: x, x^1, x^2, x^3
                const float4 v = y4[r][k];
                acc_pt += w_lds[__popc(x)]     * v.x + w_lds[__popc(x ^ 1)] * v.y
                        + w_lds[__popc(x ^ 2)] * v.z + w_lds[__popc(x ^ 3)] * v.w;
            }
            if (((t >> 2) & 63) == lane)
                acc_lg += logf(pick16(y4[r], t) + 1e-8f);
        }
    }

    // single per-wave reduction at the end
    const float invB  = 1.0f / (float)B_ROWS;
    const float invBN = 1.0f / ((float)B_ROWS * (float)N_COLS);
    float val = acc_pt * invBN - acc_lg * invB;
    #pragma unroll
    for (int m = 32; m >= 1; m >>= 1) val += __shfl_xor(val, m, 64);

    if (lane == 0) wave_part[wid] = val;
    __syncthreads();
    if (tid == 0) {
        float s = 0.0f;
        #pragma unroll
        for (int w = 0; w < WAVES_PER_BLOCK; ++w) s += wave_part[w];
        partials[blockIdx.x] = s;
    }
}

__global__ __launch_bounds__(256)
void ce_reduce_kernel(const float* __restrict__ partials, int n, float* __restrict__ out) {
    __shared__ float s[256];
    const int tid = threadIdx.x;
    float a = 0.0f;
    for (int i = tid; i < n; i += 256) a += partials[i];  // fixed order -> deterministic
    s[tid] = a;
    __syncthreads();
    for (int off = 128; off > 0; off >>= 1) {
        if (tid < off) s[tid] += s[tid + off];
        __syncthreads();
    }
    if (tid == 0) out[0] = s[0];
}

extern "C" void kernel_launch(void* const* d_in, const int* in_sizes, int n_in,
                              void* d_out, int out_size, void* d_ws, size_t ws_size,
                              hipStream_t stream) {
    const float* y_true = (const float*)d_in[0];
    const float* target = (const float*)d_in[1];
    float* out = (float*)d_out;
    float* partials = (float*)d_ws;  // ROWS_BLOCKS floats = 8 KB

    ce_rows_kernel<<<ROWS_BLOCKS, ROWS_THREADS, 0, stream>>>(y_true, target, partials);
    ce_reduce_kernel<<<1, 256, 0, stream>>>(partials, ROWS_BLOCKS, out);
}